// Round 2
// baseline (29909.879 us; speedup 1.0000x reference)
//
#include <hip/hip_runtime.h>
#include <math.h>

// RNNModel — round 2: identical to round 1 (infra failure, no counters).
// 128x128 fp32 tiles (8x8 micro) for the two dominant GEMMs
// (fused_logits 553 GF, word 410 GF) + batched transed GEMM.
// Theory: 64x64/4x4 tiles issue 16 FMA per 2 ds_read_b128 -> ~17 TF.
// 128x128/8x8 issues 64 FMA per 4 ds_read_b128 -> VALU-bound, target ~100 TF.

#define T_ 32
#define B_ 32
#define H_ 512
#define V_ 10000
#define S_ 2186
#define Z_ 20000
#define K_ 5
#define N_ (T_*B_)      // 1024
#define G4 (4*H_)       // 2048

__device__ __forceinline__ float sigm(float x) { return 1.f / (1.f + expf(-x)); }

// ---------------- fp32 GEMM 128x128, 256 thr, 8x8 micro ---------------------
// C[M,Nn] = A[M,Kk] @ B (+b1)(+b2)(ACT=1: sigmoid)
// BT=true : B is [Nn][Kk] row-major (C = A @ B^T)
// BT=false: B is [Kk][Nn] row-major
// Requirements: M % 128 == 0; Kk % 16 == 0; BT=false needs Nn % 4 == 0.
// Batched via blockIdx.z with Bstride/Cstride (element strides).
template<bool BT, int ACT>
__global__ __launch_bounds__(256) void gemm128(
    const float* __restrict__ A, const float* __restrict__ B,
    const float* __restrict__ b1, const float* __restrict__ b2,
    float* __restrict__ C, int M, int Nn, int Kk,
    long Bstride, long Cstride)
{
    B += (size_t)blockIdx.z * Bstride;
    C += (size_t)blockIdx.z * Cstride;
    const int n0 = blockIdx.x * 128;
    const int m0 = blockIdx.y * 128;
    const int tid = threadIdx.x;
    const int tx = tid & 15, ty = tid >> 4;
    __shared__ __align__(16) float As[16][132];
    __shared__ __align__(16) float Bs[16][132];
    float acc[8][8] = {};
    for (int kb = 0; kb < Kk; kb += 16) {
        // A tile: [128 rows][16 k] -> As[kk][i] (k-major)
        #pragma unroll
        for (int l = 0; l < 2; ++l) {
            int f = tid + l * 256;          // 0..511
            int i = f >> 2, q = f & 3;      // row, float4-col
            float4 v = *reinterpret_cast<const float4*>(
                &A[(size_t)(m0 + i) * Kk + kb + q * 4]);
            As[q * 4 + 0][i] = v.x;
            As[q * 4 + 1][i] = v.y;
            As[q * 4 + 2][i] = v.z;
            As[q * 4 + 3][i] = v.w;
        }
        if (BT) {
            #pragma unroll
            for (int l = 0; l < 2; ++l) {
                int f = tid + l * 256;
                int j = f >> 2, q = f & 3;
                int n = n0 + j;
                float4 v = make_float4(0.f, 0.f, 0.f, 0.f);
                if (n < Nn)
                    v = *reinterpret_cast<const float4*>(
                        &B[(size_t)n * Kk + kb + q * 4]);
                Bs[q * 4 + 0][j] = v.x;
                Bs[q * 4 + 1][j] = v.y;
                Bs[q * 4 + 2][j] = v.z;
                Bs[q * 4 + 3][j] = v.w;
            }
        } else {
            #pragma unroll
            for (int l = 0; l < 2; ++l) {
                int f = tid + l * 256;
                int kk = f >> 5, jf = f & 31;
                int n = n0 + jf * 4;
                float4 v = make_float4(0.f, 0.f, 0.f, 0.f);
                if (n < Nn)
                    v = *reinterpret_cast<const float4*>(
                        &B[(size_t)(kb + kk) * Nn + n]);
                *reinterpret_cast<float4*>(&Bs[kk][jf * 4]) = v;
            }
        }
        __syncthreads();
        #pragma unroll
        for (int kk = 0; kk < 16; ++kk) {
            float4 a0 = *reinterpret_cast<const float4*>(&As[kk][ty * 4]);
            float4 a1 = *reinterpret_cast<const float4*>(&As[kk][64 + ty * 4]);
            float4 bv0 = *reinterpret_cast<const float4*>(&Bs[kk][tx * 4]);
            float4 bv1 = *reinterpret_cast<const float4*>(&Bs[kk][64 + tx * 4]);
            float a[8] = {a0.x, a0.y, a0.z, a0.w, a1.x, a1.y, a1.z, a1.w};
            float b[8] = {bv0.x, bv0.y, bv0.z, bv0.w, bv1.x, bv1.y, bv1.z, bv1.w};
            #pragma unroll
            for (int r = 0; r < 8; ++r)
                #pragma unroll
                for (int c = 0; c < 8; ++c)
                    acc[r][c] = fmaf(a[r], b[c], acc[r][c]);
        }
        __syncthreads();
    }
    #pragma unroll
    for (int r = 0; r < 8; ++r) {
        int m = m0 + ((r < 4) ? (ty * 4 + r) : (64 + ty * 4 + r - 4));
        #pragma unroll
        for (int c = 0; c < 8; ++c) {
            int n = n0 + ((c < 4) ? (tx * 4 + c) : (64 + tx * 4 + c - 4));
            if (n < Nn) {
                float v = acc[r][c];
                if (b1) v += b1[n];
                if (b2) v += b2[n];
                if (ACT == 1) v = sigm(v);
                C[(size_t)m * Nn + n] = v;
            }
        }
    }
}

// ---------------- LSTM step -------------------------------------------------
__global__ __launch_bounds__(256) void lstm_step(
    const float* __restrict__ zx_t,   // [B][4H], biases already included
    const float* __restrict__ h_prev, // [B][H]
    const float* __restrict__ Whh,    // [4H][H]
    const float* __restrict__ c_in,   // [B][H]
    float* __restrict__ c_out,        // [B][H]
    float* __restrict__ h_out)        // [B][H] (== y[t])
{
    const int hc0 = blockIdx.x * 16;
    const int b0 = blockIdx.y * 8;
    const int tid = threadIdx.x;
    __shared__ float hs[32][9];
    __shared__ float ws[32][68];
    __shared__ float zs[8][64];
    const int cl = tid & 63;
    const int r0 = tid >> 6;
    const int g = cl >> 4, hc = cl & 15;
    const int j = g * H_ + hc0 + hc;
    float acc0 = 0.f, acc1 = 0.f;
    for (int kb = 0; kb < H_; kb += 32) {
        {
            int bl = tid >> 5, kk = tid & 31;
            hs[kk][bl] = h_prev[(size_t)(b0 + bl) * H_ + kb + kk];
        }
        #pragma unroll
        for (int l = 0; l < 8; ++l) {
            int lin = tid + l * 256;
            int cc = lin >> 5, kk = lin & 31;
            int gg = cc >> 4, hh = cc & 15;
            ws[kk][cc] = Whh[(size_t)(gg * H_ + hc0 + hh) * H_ + kb + kk];
        }
        __syncthreads();
        #pragma unroll
        for (int kk = 0; kk < 32; ++kk) {
            float w = ws[kk][cl];
            acc0 = fmaf(hs[kk][r0], w, acc0);
            acc1 = fmaf(hs[kk][r0 + 4], w, acc1);
        }
        __syncthreads();
    }
    zs[r0][cl]     = acc0 + zx_t[(size_t)(b0 + r0) * G4 + j];
    zs[r0 + 4][cl] = acc1 + zx_t[(size_t)(b0 + r0 + 4) * G4 + j];
    __syncthreads();
    if (tid < 128) {
        int bl = tid >> 4, hh = tid & 15;
        float zi = zs[bl][hh];
        float zf = zs[bl][16 + hh];
        float zg = zs[bl][32 + hh];
        float zo = zs[bl][48 + hh];
        size_t idx = (size_t)(b0 + bl) * H_ + hc0 + hh;
        float cp = c_in[idx];
        float cn = sigm(zf) * cp + sigm(zi) * tanhf(zg);
        float hn = sigm(zo) * tanhf(cn);
        c_out[idx] = cn;
        h_out[idx] = hn;
    }
}

// ---------------- fused logits: 128x64 tile, 8x4 micro ----------------------
// logits[n][z] = sum_k (transed[k][n]·ctxT[z]) * ((gate[n]⊙smw[k])·M1[:,z]) + sb[z]
__global__ __launch_bounds__(256) void fused_logits128(
    const float* __restrict__ transed, const float* __restrict__ ctxT,
    const float* __restrict__ gate, const float* __restrict__ smw,
    const float* __restrict__ M1, const float* __restrict__ sense_bias,
    float* __restrict__ logits)
{
    const int z0 = blockIdx.x * 64;
    const int n0 = blockIdx.y * 128;
    const int tid = threadIdx.x;
    const int tx = tid & 15, ty = tid >> 4;
    __shared__ __align__(16) float As[16][132];
    __shared__ __align__(16) float Bs[16][68];
    float tot[8][4] = {};
    for (int k = 0; k < K_; ++k) {
        // ---- phase 1: acc1 = transed[k] @ ctxT^T   (K = H_)
        float acc1[8][4] = {};
        const float* Ak = transed + (size_t)k * N_ * H_;
        for (int hb = 0; hb < H_; hb += 16) {
            #pragma unroll
            for (int l = 0; l < 2; ++l) {
                int f = tid + l * 256;
                int i = f >> 2, q = f & 3;
                float4 v = *reinterpret_cast<const float4*>(
                    &Ak[(size_t)(n0 + i) * H_ + hb + q * 4]);
                As[q * 4 + 0][i] = v.x;
                As[q * 4 + 1][i] = v.y;
                As[q * 4 + 2][i] = v.z;
                As[q * 4 + 3][i] = v.w;
            }
            {
                int j = tid >> 2, q = tid & 3;   // 64 rows x 4 float4
                int z = z0 + j;
                float4 v = make_float4(0.f, 0.f, 0.f, 0.f);
                if (z < Z_)
                    v = *reinterpret_cast<const float4*>(
                        &ctxT[(size_t)z * H_ + hb + q * 4]);
                Bs[q * 4 + 0][j] = v.x;
                Bs[q * 4 + 1][j] = v.y;
                Bs[q * 4 + 2][j] = v.z;
                Bs[q * 4 + 3][j] = v.w;
            }
            __syncthreads();
            #pragma unroll
            for (int kk = 0; kk < 16; ++kk) {
                float4 a0 = *reinterpret_cast<const float4*>(&As[kk][ty * 4]);
                float4 a1 = *reinterpret_cast<const float4*>(&As[kk][64 + ty * 4]);
                float4 bv = *reinterpret_cast<const float4*>(&Bs[kk][tx * 4]);
                float a[8] = {a0.x, a0.y, a0.z, a0.w, a1.x, a1.y, a1.z, a1.w};
                float b[4] = {bv.x, bv.y, bv.z, bv.w};
                #pragma unroll
                for (int r = 0; r < 8; ++r)
                    #pragma unroll
                    for (int c = 0; c < 4; ++c)
                        acc1[r][c] = fmaf(a[r], b[c], acc1[r][c]);
            }
            __syncthreads();
        }
        // ---- phase 2: acc2 = (gate ⊙ smw[k]) @ M1  (K = S_, tail-guarded)
        // gate rows are only 8B-aligned (S_=2186), so stage with float2.
        float acc2[8][4] = {};
        const float* smk = smw + (size_t)k * S_;
        for (int sb = 0; sb < S_; sb += 16) {
            #pragma unroll
            for (int l = 0; l < 4; ++l) {
                int f = tid + l * 256;          // 0..1023
                int i = f >> 3, q = f & 7;      // row, float2-col
                int s = sb + q * 2;
                float2 gv = make_float2(0.f, 0.f), wv = make_float2(0.f, 0.f);
                if (s + 1 < S_) {
                    gv = *reinterpret_cast<const float2*>(
                        &gate[(size_t)(n0 + i) * S_ + s]);
                    wv = *reinterpret_cast<const float2*>(&smk[s]);
                } else if (s < S_) {
                    gv.x = gate[(size_t)(n0 + i) * S_ + s];
                    wv.x = smk[s];
                }
                As[q * 2 + 0][i] = gv.x * wv.x;
                As[q * 2 + 1][i] = gv.y * wv.y;
            }
            {
                int kk = tid >> 4, jf = tid & 15;  // 16 k-rows x 16 float4
                int s = sb + kk;
                int z = z0 + jf * 4;
                float4 v = make_float4(0.f, 0.f, 0.f, 0.f);
                if (s < S_ && z < Z_)
                    v = *reinterpret_cast<const float4*>(
                        &M1[(size_t)s * Z_ + z]);
                *reinterpret_cast<float4*>(&Bs[kk][jf * 4]) = v;
            }
            __syncthreads();
            #pragma unroll
            for (int kk = 0; kk < 16; ++kk) {
                float4 a0 = *reinterpret_cast<const float4*>(&As[kk][ty * 4]);
                float4 a1 = *reinterpret_cast<const float4*>(&As[kk][64 + ty * 4]);
                float4 bv = *reinterpret_cast<const float4*>(&Bs[kk][tx * 4]);
                float a[8] = {a0.x, a0.y, a0.z, a0.w, a1.x, a1.y, a1.z, a1.w};
                float b[4] = {bv.x, bv.y, bv.z, bv.w};
                #pragma unroll
                for (int r = 0; r < 8; ++r)
                    #pragma unroll
                    for (int c = 0; c < 4; ++c)
                        acc2[r][c] = fmaf(a[r], b[c], acc2[r][c]);
            }
            __syncthreads();
        }
        #pragma unroll
        for (int r = 0; r < 8; ++r)
            #pragma unroll
            for (int c = 0; c < 4; ++c)
                tot[r][c] = fmaf(acc1[r][c], acc2[r][c], tot[r][c]);
    }
    #pragma unroll
    for (int r = 0; r < 8; ++r) {
        int n = n0 + ((r < 4) ? (ty * 4 + r) : (64 + ty * 4 + r - 4));
        #pragma unroll
        for (int c = 0; c < 4; ++c) {
            int z = z0 + tx * 4 + c;
            if (z < Z_)
                logits[(size_t)n * Z_ + z] = tot[r][c] + sense_bias[z];
        }
    }
}

// ---------------- row softmax over Z, in place ------------------------------
__global__ __launch_bounds__(256) void softmax_rows(float* __restrict__ p)
{
    const int n = blockIdx.x;
    float* row = p + (size_t)n * Z_;
    const int tid = threadIdx.x;
    __shared__ float red[4], red2[4];
    float m = -1e30f;
    for (int i = tid; i < Z_; i += 256) m = fmaxf(m, row[i]);
    #pragma unroll
    for (int off = 32; off; off >>= 1) m = fmaxf(m, __shfl_down(m, off, 64));
    if ((tid & 63) == 0) red[tid >> 6] = m;
    __syncthreads();
    m = fmaxf(fmaxf(red[0], red[1]), fmaxf(red[2], red[3]));
    float s = 0.f;
    for (int i = tid; i < Z_; i += 256) {
        float e = expf(row[i] - m);
        row[i] = e;
        s += e;
    }
    #pragma unroll
    for (int off = 32; off; off >>= 1) s += __shfl_down(s, off, 64);
    if ((tid & 63) == 0) red2[tid >> 6] = s;
    __syncthreads();
    float inv = 1.f / (red2[0] + red2[1] + red2[2] + red2[3]);
    for (int i = tid; i < Z_; i += 256) row[i] *= inv;
}

// ---------------- small helpers ---------------------------------------------
__global__ void smw_softmax(const float* __restrict__ mw, float* __restrict__ smw)
{
    int s = blockIdx.x * 256 + threadIdx.x;
    if (s >= S_) return;
    float w[K_];
    float m = -1e30f;
    for (int k = 0; k < K_; ++k) { w[k] = mw[k * S_ + s]; m = fmaxf(m, w[k]); }
    float sum = 0.f;
    for (int k = 0; k < K_; ++k) { w[k] = expf(w[k] - m); sum += w[k]; }
    float inv = 1.f / sum;
    for (int k = 0; k < K_; ++k) smw[k * S_ + s] = w[k] * inv;
}

__global__ void gather_rows4(const float* __restrict__ E, const int* __restrict__ idx,
                             float* __restrict__ out, int rows)
{
    int t = blockIdx.x * 256 + threadIdx.x;
    const int per = H_ / 4;  // 128 float4 per row
    if (t >= rows * per) return;
    int r = t / per, q = t % per;
    const float4* src = reinterpret_cast<const float4*>(E + (size_t)idx[r] * H_);
    reinterpret_cast<float4*>(out + (size_t)r * H_)[q] = src[q];
}

__global__ void copy_hc(const float* __restrict__ y0, const float* __restrict__ y1,
                        const float* __restrict__ cb0, const float* __restrict__ cb1,
                        float* __restrict__ out_h, float* __restrict__ out_c)
{
    int i = blockIdx.x * 256 + threadIdx.x;
    if (i >= B_ * H_) return;
    out_h[i]            = y0[(size_t)(T_ - 1) * B_ * H_ + i];
    out_h[B_ * H_ + i]  = y1[(size_t)(T_ - 1) * B_ * H_ + i];
    out_c[i]            = cb0[i];
    out_c[B_ * H_ + i]  = cb1[i];
}

// ---------------- launch ----------------------------------------------------
extern "C" void kernel_launch(void* const* d_in, const int* in_sizes, int n_in,
                              void* d_out, int out_size, void* d_ws, size_t ws_size,
                              hipStream_t stream)
{
    const int*   ids  = (const int*)  d_in[0];
    const float* h0   = (const float*)d_in[1];
    const float* c0   = (const float*)d_in[2];
    const float* E    = (const float*)d_in[3];
    const float* Wih0 = (const float*)d_in[4];
    const float* Whh0 = (const float*)d_in[5];
    const float* bih0 = (const float*)d_in[6];
    const float* bhh0 = (const float*)d_in[7];
    const float* Wih1 = (const float*)d_in[8];
    const float* Whh1 = (const float*)d_in[9];
    const float* bih1 = (const float*)d_in[10];
    const float* bhh1 = (const float*)d_in[11];
    const float* Wg   = (const float*)d_in[12];
    const float* bg   = (const float*)d_in[13];
    const float* mt   = (const float*)d_in[14];
    const float* mwt  = (const float*)d_in[15];
    const float* sb   = (const float*)d_in[16];
    const int*   widx = (const int*)  d_in[17];
    const float* M1   = (const float*)d_in[18];
    const float* M2   = (const float*)d_in[19];

    float* out      = (float*)d_out;
    float* out_word = out;                               // [N,V]
    float* out_gate = out + (size_t)N_ * V_;             // [N,S]
    float* out_h    = out_gate + (size_t)N_ * S_;        // [2,B,H]
    float* out_c    = out_h + 2 * B_ * H_;               // [2,B,H]

    float* ws = (float*)d_ws;
    float* emb     = ws; ws += (size_t)N_ * H_;
    float* zx      = ws; ws += (size_t)N_ * G4;
    float* y0      = ws; ws += (size_t)N_ * H_;
    float* y1      = ws; ws += (size_t)N_ * H_;
    float* cb0     = ws; ws += B_ * H_;
    float* cb1     = ws; ws += B_ * H_;
    float* transed = ws; ws += (size_t)K_ * N_ * H_;
    float* ctxT    = ws; ws += (size_t)Z_ * H_;
    float* logits  = ws; ws += (size_t)N_ * Z_;
    float* smw     = ws; ws += ((size_t)K_ * S_ + 3) & ~(size_t)3;

    // gathers + basis softmax (independent of LSTM)
    gather_rows4<<<(N_ * (H_ / 4) + 255) / 256, 256, 0, stream>>>(E, ids, emb, N_);
    gather_rows4<<<(Z_ * (H_ / 4) + 255) / 256, 256, 0, stream>>>(E, widx, ctxT, Z_);
    smw_softmax<<<(S_ + 255) / 256, 256, 0, stream>>>(mwt, smw);

    // ---- layer 0: Zx = emb @ Wih0^T + bih0 + bhh0, then 32 recurrent steps
    gemm128<true, 0><<<dim3(G4 / 128, N_ / 128), 256, 0, stream>>>(
        emb, Wih0, bih0, bhh0, zx, N_, G4, H_, 0, 0);
    for (int t = 0; t < T_; ++t) {
        const float* hp = t ? (y0 + (size_t)(t - 1) * B_ * H_) : h0;
        const float* ci = t ? cb0 : c0;
        lstm_step<<<dim3(32, 4), 256, 0, stream>>>(
            zx + (size_t)t * B_ * G4, hp, Whh0, ci, cb0, y0 + (size_t)t * B_ * H_);
    }
    // ---- layer 1
    gemm128<true, 0><<<dim3(G4 / 128, N_ / 128), 256, 0, stream>>>(
        y0, Wih1, bih1, bhh1, zx, N_, G4, H_, 0, 0);
    for (int t = 0; t < T_; ++t) {
        const float* hp = t ? (y1 + (size_t)(t - 1) * B_ * H_) : (h0 + B_ * H_);
        const float* ci = t ? cb1 : (c0 + B_ * H_);
        lstm_step<<<dim3(32, 4), 256, 0, stream>>>(
            zx + (size_t)t * B_ * G4, hp, Whh1, ci, cb1, y1 + (size_t)t * B_ * H_);
    }

    // gate = sigmoid(out @ Wg^T + bg)  -> straight into d_out
    gemm128<true, 1><<<dim3((S_ + 127) / 128, N_ / 128), 256, 0, stream>>>(
        y1, Wg, bg, nullptr, out_gate, N_, S_, H_, 0, 0);

    // transed[k] = out @ multi_trans[k]  — one batched launch (blockIdx.z = k)
    gemm128<false, 0><<<dim3(H_ / 128, N_ / 128, K_), 256, 0, stream>>>(
        y1, mt, nullptr, nullptr, transed, N_, H_, H_,
        (long)H_ * H_, (long)N_ * H_);

    // fused: logits[n][z] = sum_k ml*mc + sense_bias
    fused_logits128<<<dim3((Z_ + 63) / 64, N_ / 128), 256, 0, stream>>>(
        transed, ctxT, out_gate, smw, M1, sb, logits);

    // sense_prob = softmax(logits) in place
    softmax_rows<<<N_, 256, 0, stream>>>(logits);

    // word_prob = sense_prob @ M2  (NN)
    gemm128<false, 0><<<dim3((V_ + 127) / 128, N_ / 128), 256, 0, stream>>>(
        logits, M2, nullptr, nullptr, out_word, N_, V_, Z_, 0, 0);

    copy_hc<<<(B_ * H_ + 255) / 256, 256, 0, stream>>>(y0, y1, cb0, cb1, out_h, out_c);
}